// Round 2
// baseline (5081.871 us; speedup 1.0000x reference)
//
#include <hip/hip_runtime.h>
#include <cstddef>

// Problem constants (fixed by reference): B=32, NUM=64, L=256, C=HID=64, H=8
#define PAD 68                      // LDS row stride in floats: 16B-aligned (272B), 68%32=4
#define KQV_STRIDE 33554432ull      // 32*64*256*64

struct Params {
  const float *x, *emb, *Wk, *bk, *Wq, *bq, *Wv, *bv;
  const float *g0x,*b0x,*g1x,*b1x;
  const float *g0k,*b0k,*g1k,*b1k;
  const float *g0q,*b0q,*g1q,*b1q;
  const float *fx1w,*fx1b,*fx2w,*fx2b;
  const float *fk1w,*fk1b,*fk2w,*fk2b;
  const float *fq1w,*fq1b,*fq2w,*fq2b;
  float *K, *Q, *V;
};

static __device__ __forceinline__ void load_xe(const Params& p, int b, int t, int l, float* xe) {
  const float4* xr = (const float4*)(p.x + ((((size_t)b*64 + t)*256) + l)*64);
  const float4* er = (const float4*)(p.emb + (size_t)l*64);
  #pragma unroll
  for (int i = 0; i < 16; ++i) {
    float4 a = xr[i], e = er[i];
    xe[4*i+0] = a.x + e.x; xe[4*i+1] = a.y + e.y;
    xe[4*i+2] = a.z + e.z; xe[4*i+3] = a.w + e.w;
  }
}

// per-head 8x8 linear: out[h*8+e] = bias[h,e] + sum_d xe[h*8+d]*W[h,d,e]
static __device__ __forceinline__ void raw_proj(const float* xe, const float* __restrict__ W,
                                                const float* __restrict__ bi, float* out) {
  #pragma unroll
  for (int h = 0; h < 8; ++h) {
    #pragma unroll
    for (int e = 0; e < 8; ++e) {
      float acc = bi[h*8+e];
      #pragma unroll
      for (int d = 0; d < 8; ++d) acc += xe[h*8+d] * W[h*64 + d*8 + e];
      out[h*8+e] = acc;
    }
  }
}

// t = 0: outputs are the raw projections (scan starts at x[:,1:])
__global__ __launch_bounds__(256, 1)
void t0_kernel(Params p) {
  const int b = blockIdx.x, j = threadIdx.x;
  float xe[64], kr[64], qr[64], vr[64];
  load_xe(p, b, 0, j, xe);
  raw_proj(xe, p.Wk, p.bk, kr);
  raw_proj(xe, p.Wq, p.bq, qr);
  raw_proj(xe, p.Wv, p.bv, vr);
  const size_t off = (((size_t)b*64 + 0)*256 + j)*64;
  #pragma unroll
  for (int i = 0; i < 16; ++i) {
    ((float4*)(p.K + off))[i] = make_float4(kr[4*i], kr[4*i+1], kr[4*i+2], kr[4*i+3]);
    ((float4*)(p.Q + off))[i] = make_float4(qr[4*i], qr[4*i+1], qr[4*i+2], qr[4*i+3]);
    ((float4*)(p.V + off))[i] = make_float4(vr[4*i], vr[4*i+1], vr[4*i+2], vr[4*i+3]);
  }
}

// One cross_attn, 64 output rows per block.
// mode 0 (k-path): Ksrc=Vsrc=kraw(t), Q=Qout[t-1], params *k, out -> K[t]
// mode 1 (q-path): Ksrc=Kout[t-1], Vsrc=qraw(t), Q=qraw(t), params *q, out -> Q[t]
// mode 2 (v-path): Ksrc=Kout[t],   Vsrc=vraw(t), Q=Qout[t], params *x, out -> V[t]
__global__ __launch_bounds__(256, 1)
void ca_kernel(Params p, int t_arg, int phaseB) {
  __shared__ float Kb[256*PAD];   // K tile; later: O-partials (rows c*64+r), then zT (rows 0..63)
  __shared__ float Vb[256*PAD];   // V tile; later rows 0..63 overlaid by f1T
  __shared__ float lred[256];     // softmax-denominator partials, [c][r] (lane-stride 1)
  __shared__ float red[512];      // LN reduce, [c][r*2+{0,1}] (lane-stride 2)

  const int bid = blockIdx.x;
  int mode, t;
  if (!phaseB) { t = t_arg; mode = bid >> 7; }   // blocks 0..127 kpath, 128..255 qpath
  else         { t = 1 + (bid >> 7); mode = 2; } // 63*128 blocks
  const int r128 = bid & 127;
  const int b  = r128 >> 2;
  const int rc = r128 & 3;

  const float *g0,*b0,*g1,*b1,*W1,*bb1,*W2,*bb2;
  if (mode == 0)      { g0=p.g0k; b0=p.b0k; g1=p.g1k; b1=p.b1k; W1=p.fk1w; bb1=p.fk1b; W2=p.fk2w; bb2=p.fk2b; }
  else if (mode == 1) { g0=p.g0q; b0=p.b0q; g1=p.g1q; b1=p.b1q; W1=p.fq1w; bb1=p.fq1b; W2=p.fq2w; bb2=p.fq2b; }
  else                { g0=p.g0x; b0=p.b0x; g1=p.g1x; b1=p.b1x; W1=p.fx1w; bb1=p.fx1b; W2=p.fx2w; bb2=p.fx2b; }

  const int tid = threadIdx.x;
  const int r = tid & 63, c = tid >> 6;     // wave = quarter c -> K/V tile reads broadcast
  const int row = rc*64 + r;

  // ---- stage K/V tiles: thread stages row j = tid ----
  {
    const int j = tid;
    if (mode == 0) {
      float xe[64], kr[64];
      load_xe(p, b, t, j, xe);
      raw_proj(xe, p.Wk, p.bk, kr);
      #pragma unroll
      for (int i = 0; i < 16; ++i) {
        float4 v4 = make_float4(kr[4*i], kr[4*i+1], kr[4*i+2], kr[4*i+3]);
        *(float4*)(&Kb[j*PAD + 4*i]) = v4;
        *(float4*)(&Vb[j*PAD + 4*i]) = v4;
      }
    } else {
      const float4* src = (const float4*)(p.K + (((size_t)b*64 + (mode==1 ? t-1 : t))*256 + j)*64);
      #pragma unroll
      for (int i = 0; i < 16; ++i) *(float4*)(&Kb[j*PAD + 4*i]) = src[i];
      float xe[64], vv[64];
      load_xe(p, b, t, j, xe);
      raw_proj(xe, (mode==1 ? p.Wq : p.Wv), (mode==1 ? p.bq : p.bv), vv);
      #pragma unroll
      for (int i = 0; i < 16; ++i)
        *(float4*)(&Vb[j*PAD + 4*i]) = make_float4(vv[4*i], vv[4*i+1], vv[4*i+2], vv[4*i+3]);
    }
  }

  // ---- Q row for this thread's output row ----
  float Qr[64];
  if (mode == 1) {
    float xe[64];
    load_xe(p, b, t, row, xe);
    raw_proj(xe, p.Wq, p.bq, Qr);
  } else {
    const float4* qsrc = (const float4*)(p.Q + (((size_t)b*64 + (mode==0 ? t-1 : t))*256 + row)*64);
    #pragma unroll
    for (int i = 0; i < 16; ++i) {
      float4 q4 = qsrc[i];
      Qr[4*i] = q4.x; Qr[4*i+1] = q4.y; Qr[4*i+2] = q4.z; Qr[4*i+3] = q4.w;
    }
  }
  __syncthreads();

  // ---- fused S + PV over this quarter's 64 keys ----
  // No max-subtraction needed: |s| <= |q||k| = 64 exactly (rows are LN'd), and
  // e^64 * 256 ~ 1.6e30 < fp32 max -> single-pass exp-sum is safe.
  float O[64];
  #pragma unroll
  for (int i = 0; i < 64; ++i) O[i] = 0.f;
  float l = 0.f;
  #pragma unroll 2
  for (int jq = 0; jq < 64; ++jq) {
    const float* Kr = &Kb[(c*64 + jq)*PAD];   // wave-uniform address -> broadcast
    float s0=0.f, s1=0.f, s2=0.f, s3=0.f;     // 4 chains: break FMA dependency
    #pragma unroll
    for (int d4 = 0; d4 < 16; ++d4) {
      float4 k4 = *(const float4*)(Kr + 4*d4);
      s0 += Qr[4*d4+0]*k4.x; s1 += Qr[4*d4+1]*k4.y;
      s2 += Qr[4*d4+2]*k4.z; s3 += Qr[4*d4+3]*k4.w;
    }
    float pw = __expf((s0+s1)+(s2+s3));
    l += pw;
    const float* Vr = &Vb[(c*64 + jq)*PAD];   // wave-uniform address -> broadcast
    #pragma unroll
    for (int d4 = 0; d4 < 16; ++d4) {
      float4 v4 = *(const float4*)(Vr + 4*d4);
      O[4*d4+0] += pw*v4.x; O[4*d4+1] += pw*v4.y;
      O[4*d4+2] += pw*v4.z; O[4*d4+3] += pw*v4.w;
    }
  }
  lred[c*64 + r] = l;   // [c][r]: lane-stride 1
  {  // O partials overlay Kb rows [c*64, c*64+64): own quarter only; within-wave
     // lockstep means all lanes finished reading this quarter before any store.
    float* Op = &Kb[(c*64 + r)*PAD];
    #pragma unroll
    for (int d4 = 0; d4 < 16; ++d4)
      *(float4*)(Op + 4*d4) = make_float4(O[4*d4], O[4*d4+1], O[4*d4+2], O[4*d4+3]);
  }
  __syncthreads();

  // ---- merge quarters; z = out*inv + v; thread (r,c) owns dims [16c,16c+16) ----
  const int eb  = c*16;
  const int ebs = __builtin_amdgcn_readfirstlane(eb);  // scalar -> s_load for params
  const float lt  = lred[0*64+r] + lred[1*64+r] + lred[2*64+r] + lred[3*64+r];
  const float inv = 1.0f / (lt * 8.0f);                // softmax then /sqrt(64)
  float zv[16], zn[16];
  float sm = 0.f, sq = 0.f;
  const float4* vres = (const float4*)(&Vb[row*PAD + eb]);
  #pragma unroll
  for (int k4 = 0; k4 < 4; ++k4) {
    float4 o = *(const float4*)(&Kb[(0*64+r)*PAD + eb + 4*k4]);
    #pragma unroll
    for (int cc = 1; cc < 4; ++cc) {
      float4 tpart = *(const float4*)(&Kb[(cc*64+r)*PAD + eb + 4*k4]);
      o.x += tpart.x; o.y += tpart.y; o.z += tpart.z; o.w += tpart.w;
    }
    float4 v4 = vres[k4];
    float4 z4 = make_float4(o.x*inv + v4.x, o.y*inv + v4.y, o.z*inv + v4.z, o.w*inv + v4.w);
    zv[4*k4+0]=z4.x; zv[4*k4+1]=z4.y; zv[4*k4+2]=z4.z; zv[4*k4+3]=z4.w;
    sm += z4.x+z4.y+z4.z+z4.w;
    sq += z4.x*z4.x + z4.y*z4.y + z4.z*z4.z + z4.w*z4.w;
  }
  red[c*128 + r*2 + 0] = sm; red[c*128 + r*2 + 1] = sq;
  __syncthreads();
  {
    float s_ = 0.f, q_ = 0.f;
    #pragma unroll
    for (int cc = 0; cc < 4; ++cc) { s_ += red[cc*128 + r*2]; q_ += red[cc*128 + r*2 + 1]; }
    const float mean = s_*(1.f/64.f);
    const float var  = q_*(1.f/64.f) - mean*mean;
    const float rs   = rsqrtf(var + 1e-5f);
    const float* g0p = g0 + ebs; const float* b0p = b0 + ebs;
    #pragma unroll
    for (int i = 0; i < 16; ++i) zn[i] = (zv[i] - mean)*rs*g0p[i] + b0p[i];
  }
  // zT overlay: z stored TRANSPOSED at Kb[d][r] (rows 0..63) -> all FFN1 reads
  // and these writes are lane-stride-1, conflict-free. O-partials in rows 0..63
  // were fully consumed before the barrier above.
  #pragma unroll
  for (int i = 0; i < 16; ++i) Kb[(eb+i)*PAD + r] = zn[i];
  __syncthreads();

  // ---- FFN1: f1 = relu(z @ W1 + b1); W via wave-uniform scalar loads ----
  float f1[16];
  {
    const float* W1p = W1 + ebs; const float* bb1p = bb1 + ebs;
    #pragma unroll
    for (int i = 0; i < 16; ++i) f1[i] = bb1p[i];
    for (int d = 0; d < 64; ++d) {
      const float zd = Kb[d*PAD + r];          // lane-stride 1: conflict-free
      #pragma unroll
      for (int i = 0; i < 16; ++i) f1[i] += zd * W1p[d*64 + i];
    }
    #pragma unroll
    for (int i = 0; i < 16; ++i) f1[i] = fmaxf(f1[i], 0.f);
  }
  // f1T overlay on Vb rows 0..63 (all Vb data reads happened before the z barrier)
  #pragma unroll
  for (int i = 0; i < 16; ++i) Vb[(eb+i)*PAD + r] = f1[i];
  __syncthreads();

  // ---- FFN2 + residual + LN2 ----
  float y[16];
  {
    const float* W2p = W2 + ebs; const float* bb2p = bb2 + ebs;
    #pragma unroll
    for (int i = 0; i < 16; ++i) y[i] = bb2p[i];
    for (int d = 0; d < 64; ++d) {
      const float fd = Vb[d*PAD + r];          // lane-stride 1: conflict-free
      #pragma unroll
      for (int i = 0; i < 16; ++i) y[i] += fd * W2p[d*64 + i];
    }
    #pragma unroll
    for (int i = 0; i < 16; ++i) y[i] += zn[i];
  }
  float s2_ = 0.f, q2_ = 0.f;
  #pragma unroll
  for (int i = 0; i < 16; ++i) { s2_ += y[i]; q2_ += y[i]*y[i]; }
  red[c*128 + r*2 + 0] = s2_; red[c*128 + r*2 + 1] = q2_;
  __syncthreads();
  {
    float sa = 0.f, qa = 0.f;
    #pragma unroll
    for (int cc = 0; cc < 4; ++cc) { sa += red[cc*128 + r*2]; qa += red[cc*128 + r*2 + 1]; }
    const float mean2 = sa*(1.f/64.f);
    const float var2  = qa*(1.f/64.f) - mean2*mean2;
    const float rs2   = rsqrtf(var2 + 1e-5f);
    const float* g1p = g1 + ebs; const float* b1p = b1 + ebs;
    float* dst = (mode==0 ? p.K : (mode==1 ? p.Q : p.V))
               + (((size_t)b*64 + t)*256 + row)*64 + eb;
    #pragma unroll
    for (int d4 = 0; d4 < 4; ++d4) {
      float4 o4;
      o4.x = (y[4*d4+0]-mean2)*rs2*g1p[4*d4+0] + b1p[4*d4+0];
      o4.y = (y[4*d4+1]-mean2)*rs2*g1p[4*d4+1] + b1p[4*d4+1];
      o4.z = (y[4*d4+2]-mean2)*rs2*g1p[4*d4+2] + b1p[4*d4+2];
      o4.w = (y[4*d4+3]-mean2)*rs2*g1p[4*d4+3] + b1p[4*d4+3];
      ((float4*)dst)[d4] = o4;
    }
  }
}

extern "C" void kernel_launch(void* const* d_in, const int* in_sizes, int n_in,
                              void* d_out, int out_size, void* d_ws, size_t ws_size,
                              hipStream_t stream) {
  (void)in_sizes; (void)n_in; (void)out_size; (void)d_ws; (void)ws_size;
  Params p;
  p.x   =(const float*)d_in[0];  p.emb =(const float*)d_in[1];
  p.Wk  =(const float*)d_in[2];  p.bk  =(const float*)d_in[3];
  p.Wq  =(const float*)d_in[4];  p.bq  =(const float*)d_in[5];
  p.Wv  =(const float*)d_in[6];  p.bv  =(const float*)d_in[7];
  p.g0x =(const float*)d_in[8];  p.b0x =(const float*)d_in[9];
  p.g1x =(const float*)d_in[10]; p.b1x =(const float*)d_in[11];
  p.g0k =(const float*)d_in[12]; p.b0k =(const float*)d_in[13];
  p.g1k =(const float*)d_in[14]; p.b1k =(const float*)d_in[15];
  p.g0q =(const float*)d_in[16]; p.b0q =(const float*)d_in[17];
  p.g1q =(const float*)d_in[18]; p.b1q =(const float*)d_in[19];
  p.fx1w=(const float*)d_in[20]; p.fx1b=(const float*)d_in[21];
  p.fx2w=(const float*)d_in[22]; p.fx2b=(const float*)d_in[23];
  p.fk1w=(const float*)d_in[24]; p.fk1b=(const float*)d_in[25];
  p.fk2w=(const float*)d_in[26]; p.fk2b=(const float*)d_in[27];
  p.fq1w=(const float*)d_in[28]; p.fq1b=(const float*)d_in[29];
  p.fq2w=(const float*)d_in[30]; p.fq2b=(const float*)d_in[31];
  float* out = (float*)d_out;
  p.K = out; p.Q = out + KQV_STRIDE; p.V = out + 2*KQV_STRIDE;

  // t=0: raw projections
  hipLaunchKernelGGL(t0_kernel, dim3(32), dim3(256), 0, stream, p);
  // phase A: sequential recurrence; k-path and q-path of step t in one launch
  for (int t = 1; t < 64; ++t)
    hipLaunchKernelGGL(ca_kernel, dim3(256), dim3(256), 0, stream, p, t, 0);
  // phase B: all v-paths for t=1..63, fully parallel
  hipLaunchKernelGGL(ca_kernel, dim3(63*128), dim3(256), 0, stream, p, 0, 1);
}